// Round 9
// baseline (1356.457 us; speedup 1.0000x reference)
//
#include <hip/hip_runtime.h>
#include <math.h>

static constexpr float EPS_SK = 0.02f;
static constexpr float LOG2E  = 1.4426950408889634f;
static constexpr float LN2F   = 0.6931471805599453f;
#define LOGN1 6.931471805599453f   /* log 1024 */
#define LOGN2 8.317766166719343f   /* log 4096 */

__device__ __forceinline__ float fexp2(float x){ return __builtin_amdgcn_exp2f(x); }
__device__ __forceinline__ float flog2(float x){ return __builtin_amdgcn_logf(x); }

using f32x2 = __attribute__((ext_vector_type(2))) float;

// ============ LDS union padded >80KB => exactly 1 block/CU; 194 blocks co-resident ====
union Lds {
  struct {
    float sx[4096], sy[4096], sz[4096];     // 48 KB staged points
    unsigned long long slot[8];             // [parity][wave] exchange slots
  } fps;
  struct { float tyx[1024], tyy[1024], tyz[1024], tg[1024]; } emd;
  struct { float x[1024], y[1024], z[1024]; } ch;
  float pad[21000];                          // 84000 B -> 1 block/CU
};

// ---------------- sync primitives (validated R5-R8) ----------------
__device__ __forceinline__ void gbar(unsigned* cnt, unsigned* gen, unsigned nblk) {
  __threadfence();
  __syncthreads();
  if (threadIdx.x == 0) {
    unsigned g = __hip_atomic_load(gen, __ATOMIC_ACQUIRE, __HIP_MEMORY_SCOPE_AGENT);
    if (__hip_atomic_fetch_add(cnt, 1u, __ATOMIC_ACQ_REL, __HIP_MEMORY_SCOPE_AGENT) == nblk - 1u) {
      __hip_atomic_store(cnt, 0u, __ATOMIC_RELAXED, __HIP_MEMORY_SCOPE_AGENT);
      __hip_atomic_fetch_add(gen, 1u, __ATOMIC_ACQ_REL, __HIP_MEMORY_SCOPE_AGENT);
    } else {
      while (__hip_atomic_load(gen, __ATOMIC_ACQUIRE, __HIP_MEMORY_SCOPE_AGENT) == g)
        __builtin_amdgcn_s_sleep(8);
    }
  }
  __syncthreads();
  __threadfence();
}

__device__ __forceinline__ void signal_done(unsigned* f) {
  __threadfence();
  __syncthreads();
  if (threadIdx.x == 0)
    __hip_atomic_fetch_add(f, 1u, __ATOMIC_RELEASE, __HIP_MEMORY_SCOPE_AGENT);
}

__device__ __forceinline__ void waitcnt_ge(unsigned* f, unsigned target) {
  if (threadIdx.x == 0)
    while (__hip_atomic_load(f, __ATOMIC_ACQUIRE, __HIP_MEMORY_SCOPE_AGENT) < target)
      __builtin_amdgcn_s_sleep(16);
  __syncthreads();
  __threadfence();
}

// DPP helpers: shifted-lane copies (old=self => invalid lanes are no-ops)
template<int C>
__device__ __forceinline__ float dppf(float x) {
  return __int_as_float(__builtin_amdgcn_update_dpp(
      __float_as_int(x), __float_as_int(x), C, 0xF, 0xF, false));
}
template<int C>
__device__ __forceinline__ int dppi(int x) {
  return __builtin_amdgcn_update_dpp(x, x, C, 0xF, 0xF, false);
}
__device__ __forceinline__ float wave_max_to_l63(float v) {
  v = fmaxf(v, dppf<0x111>(v));  // row_shr:1
  v = fmaxf(v, dppf<0x112>(v));  // row_shr:2
  v = fmaxf(v, dppf<0x114>(v));  // row_shr:4
  v = fmaxf(v, dppf<0x118>(v));  // row_shr:8
  v = fmaxf(v, dppf<0x142>(v));  // row_bcast15
  v = fmaxf(v, dppf<0x143>(v));  // row_bcast31
  return v;                      // lane 63 holds wave max
}
__device__ __forceinline__ int wave_min_to_l63(int v) {
  v = min(v, dppi<0x111>(v));
  v = min(v, dppi<0x112>(v));
  v = min(v, dppi<0x114>(v));
  v = min(v, dppi<0x118>(v));
  v = min(v, dppi<0x142>(v));
  v = min(v, dppi<0x143>(v));
  return v;
}

// -------- FPS: 4 waves per batch, 16 pts/lane packed f32x2 (64 VGPR resident),
// NO barriers in loop. Cross-wave combine via 4 tagged parity-buffered LDS slots.
// slot packing: [Mbits:32][tag s:12 @bit12][idx:12 @bit0]; init ~0 => tag 0xFFF never matches.
__device__ __forceinline__ void fps_body4(Lds& L, const float* __restrict__ gt,
                                          float* __restrict__ gt_fps,
                                          unsigned* __restrict__ fpsflag, int b) {
  const int t = threadIdx.x;
  const float* P = gt + (size_t)b*4096*3;
  for (int i = t; i < 4096; i += 512) {
    L.fps.sx[i] = P[i*3+0]; L.fps.sy[i] = P[i*3+1]; L.fps.sz[i] = P[i*3+2];
  }
  if (t < 8) L.fps.slot[t] = ~0ull;
  __syncthreads();                      // all 8 waves staged; waves 4..7 exit after
  if (t >= 256) return;
  const int w = t >> 6;                 // wave 0..3, owns points [w*1024, w*1024+1024)
  const int lane = t & 63;
  const int base0 = w*1024 + 2*lane;    // idx = base0 + p*128 + half (ascending in (p,lane,half))
  f32x2 px[8], py[8], pz[8], d2[8];
#pragma unroll
  for (int p = 0; p < 8; ++p) {
    const int i0 = base0 + p*128;
    px[p] = *(const f32x2*)&L.fps.sx[i0];
    py[p] = *(const f32x2*)&L.fps.sy[i0];
    pz[p] = *(const f32x2*)&L.fps.sz[i0];
    d2[p].x = 1e10f; d2[p].y = 1e10f;   // matches reference init
  }
  float cx = L.fps.sx[0], cy = L.fps.sy[0], cz = L.fps.sz[0];
  if (t == 0) {
    float* o = gt_fps + (size_t)b*3072;
    o[0] = cx; o[1] = cy; o[2] = cz;
  }
  volatile unsigned long long* slots = L.fps.slot;
  for (int s = 1; s < 1024; ++s) {
    f32x2 bv2; bv2.x = -1.0f; bv2.y = -1.0f;
    {
#pragma clang fp contract(off)
      f32x2 c2x; c2x.x = cx; c2x.y = cx;
      f32x2 c2y; c2y.x = cy; c2y.y = cy;
      f32x2 c2z; c2z.x = cz; c2z.y = cz;
#pragma unroll
      for (int p = 0; p < 8; ++p) {
        f32x2 dx = px[p]-c2x, dy = py[p]-c2y, dz = pz[p]-c2z;
        f32x2 d  = dx*dx + dy*dy + dz*dz;          // pk mul/add, IEEE-exact per lane
        f32x2 nd = __builtin_elementwise_min(d2[p], d);
        d2[p] = nd;
        bv2 = __builtin_elementwise_max(bv2, nd);
      }
    }
    float bv = fmaxf(bv2.x, bv2.y);
    bv = wave_max_to_l63(bv);
    const unsigned Mbits = (unsigned)__builtin_amdgcn_readlane(__float_as_int(bv), 63);
    const float M = __uint_as_float(Mbits);
    // exact-compare index scan; min matching global idx == first occurrence
    int ic = 0x7FFFFFFF;
#pragma unroll
    for (int p = 0; p < 8; ++p) {
      const int i0 = base0 + p*128;
      if (d2[p].x == M) ic = min(ic, i0);
      if (d2[p].y == M) ic = min(ic, i0 + 1);
    }
    ic = wave_min_to_l63(ic);
    const int widx = __builtin_amdgcn_readlane(ic, 63);
    const int par = (s & 1) * 4;
    if (lane == 0)
      slots[par + w] = (((unsigned long long)Mbits) << 32)
                       | ((unsigned)s << 12) | (unsigned)widx;
    unsigned long long v0, v1, v2, v3;
    const unsigned tg = (unsigned)s;
    for (;;) {
      v0 = slots[par + 0]; v1 = slots[par + 1];
      v2 = slots[par + 2]; v3 = slots[par + 3];
      if ((((unsigned)(v0 >> 12)) & 0xFFFu) == tg &&
          (((unsigned)(v1 >> 12)) & 0xFFFu) == tg &&
          (((unsigned)(v2 >> 12)) & 0xFFFu) == tg &&
          (((unsigned)(v3 >> 12)) & 0xFFFu) == tg) break;
    }
    float bM = __uint_as_float((unsigned)(v0 >> 32)); int bI = (int)(v0 & 0xFFFu);
    {
      float m1 = __uint_as_float((unsigned)(v1 >> 32)); int i1 = (int)(v1 & 0xFFFu);
      if (m1 > bM || (m1 == bM && i1 < bI)) { bM = m1; bI = i1; }
      float m2 = __uint_as_float((unsigned)(v2 >> 32)); int i2 = (int)(v2 & 0xFFFu);
      if (m2 > bM || (m2 == bM && i2 < bI)) { bM = m2; bI = i2; }
      float m3 = __uint_as_float((unsigned)(v3 >> 32)); int i3 = (int)(v3 & 0xFFFu);
      if (m3 > bM || (m3 == bM && i3 < bI)) { bM = m3; bI = i3; }
    }
    cx = L.fps.sx[bI]; cy = L.fps.sy[bI]; cz = L.fps.sz[bI];
    if (t == 0) {
      float* o = gt_fps + (size_t)b*3072 + s*3;
      o[0] = cx; o[1] = cy; o[2] = cz;
    }
  }
  if (t == 0) {
    __threadfence();
    __hip_atomic_fetch_add(&fpsflag[b], 1u, __ATOMIC_RELEASE, __HIP_MEMORY_SCOPE_AGENT);
  }
}

// ============== EMD bodies, 512 threads, JPW rows/wave, masked row wrap (proven) ====
template<int JPW>
__device__ __forceinline__ void emd_pass_t(
    const float* __restrict__ xb, int xm,
    const float* __restrict__ yb, int ym,
    const float* __restrict__ vinb, float* __restrict__ voutb,
    int N, float logN, int use_vin, int r0b,
    float* tyx, float* tyy, float* tyz, float* tg)
{
  const int t = threadIdx.x;
  const int lane = t & 63;
  const int wv   = t >> 6;
  const int r0 = r0b + wv*JPW;
  float px[JPW], py[JPW], pz[JPW], mx[JPW], sm[JPW];
#pragma unroll
  for (int j = 0; j < JPW; ++j) {
    const int row = (r0 + j) & xm;
    const float* xp = xb + (size_t)row*3;
    px[j] = xp[0]; py[j] = xp[1]; pz[j] = xp[2];
    mx[j] = -3.4e38f; sm[j] = 0.0f;
  }
  const float S = LOG2E / EPS_SK;
  const int ntiles = N >> 10;
  for (int tt = 0; tt < ntiles; ++tt) {
    const int base = tt << 10;
    __syncthreads();
    for (int i = t; i < 1024; i += 512) {
      const int row = (base + i) & ym;
      const float* yp = yb + (size_t)row*3;
      tyx[i] = yp[0]; tyy[i] = yp[1]; tyz[i] = yp[2];
      tg[i]  = use_vin ? vinb[base + i] : 0.0f;
    }
    __syncthreads();
    for (int mi = lane; mi < 1024; mi += 64) {
      float yx = tyx[mi], yy = tyy[mi], yz = tyz[mi], g = tg[mi];
#pragma unroll
      for (int j = 0; j < JPW; ++j) {
        float dx = px[j]-yx, dy = py[j]-yy, dz = pz[j]-yz;
        float d  = dx*dx + dy*dy + dz*dz;
        float tv = (g - d) * S;
        float nm = fmaxf(mx[j], tv);
        sm[j] = sm[j]*fexp2(mx[j]-nm) + fexp2(tv-nm);
        mx[j] = nm;
      }
    }
  }
#pragma unroll
  for (int j = 0; j < JPW; ++j) {
#pragma unroll
    for (int off = 1; off < 64; off <<= 1) {
      float om = __shfl_xor(mx[j], off, 64);
      float os = __shfl_xor(sm[j], off, 64);
      float nm = fmaxf(mx[j], om);
      sm[j] = sm[j]*fexp2(mx[j]-nm) + os*fexp2(om-nm);
      mx[j] = nm;
    }
  }
  if (lane == 0) {
#pragma unroll
    for (int j = 0; j < JPW; ++j) {
      float lse = (mx[j] + flog2(sm[j])) * LN2F;
      voutb[r0 + j] = -EPS_SK * (lse + logN);
    }
  }
}

template<int JPW>
__device__ __forceinline__ void emd_final_t(
    const float* __restrict__ xb, int xm,
    const float* __restrict__ yb, int ym,
    const float* __restrict__ ginb, float* __restrict__ doutb,
    int N, int use_g, int r0b,
    float* tyx, float* tyy, float* tyz, float* tg)
{
  const int t = threadIdx.x;
  const int lane = t & 63;
  const int wv   = t >> 6;
  const int r0 = r0b + wv*JPW;
  float px[JPW], py[JPW], pz[JPW], mx[JPW], sm[JPW], wc[JPW];
#pragma unroll
  for (int j = 0; j < JPW; ++j) {
    const int row = (r0 + j) & xm;
    const float* xp = xb + (size_t)row*3;
    px[j] = xp[0]; py[j] = xp[1]; pz[j] = xp[2];
    mx[j] = -3.4e38f; sm[j] = 0.0f; wc[j] = 0.0f;
  }
  const float S = LOG2E / EPS_SK;
  const int ntiles = N >> 10;
  for (int tt = 0; tt < ntiles; ++tt) {
    const int base = tt << 10;
    __syncthreads();
    for (int i = t; i < 1024; i += 512) {
      const int row = (base + i) & ym;
      const float* yp = yb + (size_t)row*3;
      tyx[i] = yp[0]; tyy[i] = yp[1]; tyz[i] = yp[2];
      tg[i]  = use_g ? ginb[base + i] : 0.0f;
    }
    __syncthreads();
    for (int mi = lane; mi < 1024; mi += 64) {
      float yx = tyx[mi], yy = tyy[mi], yz = tyz[mi], g = tg[mi];
#pragma unroll
      for (int j = 0; j < JPW; ++j) {
        float dx = px[j]-yx, dy = py[j]-yy, dz = pz[j]-yz;
        float d  = dx*dx + dy*dy + dz*dz;
        float tv = (g - d) * S;
        float nm = fmaxf(mx[j], tv);
        float r  = fexp2(mx[j]-nm);
        float e  = fexp2(tv-nm);
        sm[j] = sm[j]*r + e;
        wc[j] = wc[j]*r + e*d;
        mx[j] = nm;
      }
    }
  }
#pragma unroll
  for (int j = 0; j < JPW; ++j) {
#pragma unroll
    for (int off = 1; off < 64; off <<= 1) {
      float om = __shfl_xor(mx[j], off, 64);
      float os = __shfl_xor(sm[j], off, 64);
      float ow = __shfl_xor(wc[j], off, 64);
      float nm = fmaxf(mx[j], om);
      float r1 = fexp2(mx[j]-nm);
      float r2 = fexp2(om-nm);
      sm[j] = sm[j]*r1 + os*r2;
      wc[j] = wc[j]*r1 + ow*r2;
      mx[j] = nm;
    }
  }
  if (lane == 0) {
#pragma unroll
    for (int j = 0; j < JPW; ++j)
      doutb[r0 + j] = sqrtf(wc[j] / sm[j]);
  }
}

__device__ __forceinline__ float blk_sum512(float v, float* lds) {
#pragma unroll
  for (int off = 32; off >= 1; off >>= 1) v += __shfl_xor(v, off, 64);
  int lane = threadIdx.x & 63, wv = threadIdx.x >> 6;
  __syncthreads();
  if (lane == 0) lds[wv] = v;
  __syncthreads();
  return lds[0]+lds[1]+lds[2]+lds[3]+lds[4]+lds[5]+lds[6]+lds[7];
}

__device__ __forceinline__ void finalize_body(int b,
    const float* __restrict__ A, const float* __restrict__ B,
    const float* __restrict__ C, const float* __restrict__ D,
    const float* __restrict__ dv1, const float* __restrict__ dv2,
    float* __restrict__ out, float* lds) {
  const int t = threadIdx.x;
  float e1 = 0, e2 = 0;
  for (int i = t; i < 1024; i += 512) e1 += dv1[b*1024+i];
  e1 = blk_sum512(e1, lds);
  for (int i = t; i < 4096; i += 512) e2 += dv2[b*4096+i];
  e2 = blk_sum512(e2, lds);
  float rA=0, sA=0, rB=0, sB=0, rC=0, sC=0, rD=0, sD=0;
  for (int i = t; i < 4096; i += 512) { float v = A[b*4096+i]; rA += v; sA += sqrtf(v); }
  rA = blk_sum512(rA, lds); sA = blk_sum512(sA, lds);
  for (int i = t; i < 512;  i += 512) { float v = B[b*512+i];  rB += v; sB += sqrtf(v); }
  rB = blk_sum512(rB, lds); sB = blk_sum512(sB, lds);
  for (int i = t; i < 4096; i += 512) { float v = C[b*4096+i]; rC += v; sC += sqrtf(v); }
  rC = blk_sum512(rC, lds); sC = blk_sum512(sC, lds);
  for (int i = t; i < 4096; i += 512) { float v = D[b*4096+i]; rD += v; sD += sqrtf(v); }
  rD = blk_sum512(rD, lds); sD = blk_sum512(sD, lds);
  if (t == 0) {
    out[27648 + b] = e1 / 1024.0f;
    out[27650 + b] = e2 / 4096.0f;
    out[27652 + b] = 0.5f*(sA/4096.0f + sB/512.0f);
    out[27654 + b] = 0.5f*(sC/4096.0f + sD/4096.0f);
    out[27656 + b] = rA/4096.0f + rB/512.0f;
    out[27658 + b] = rC/4096.0f + rD/4096.0f;
  }
}

// ---- tiny init: zero the 8 sync words (replay-safe) ----
__global__ void init_sync(unsigned* __restrict__ sync) {
  if (threadIdx.x < 8)
    __hip_atomic_store(&sync[threadIdx.x], 0u, __ATOMIC_RELAXED, __HIP_MEMORY_SCOPE_AGENT);
}

// ===================== the one big kernel: 194 blocks x 512 ====================
// blk 0-1: FPS (4-wave, barrier-free loop)
// blk 2-129: EMD2 persistent (128 blocks x 64 rows)
// blk 130-193: chamfer(50)/copies(14) first, then EMD1 (64 blocks x 32 rows), finalize
__global__ __launch_bounds__(512, 2) void everything(
    const float* __restrict__ coarse, const float* __restrict__ fine,
    const float* __restrict__ gt, const int* __restrict__ itersPtr,
    float* __restrict__ chamA, float* __restrict__ chamB,
    float* __restrict__ chamC, float* __restrict__ chamD,
    float* __restrict__ f1, float* __restrict__ g1, float* __restrict__ dv1,
    float* __restrict__ f2, float* __restrict__ g2, float* __restrict__ dv2,
    float* __restrict__ gtfps, unsigned* __restrict__ sync,
    float* __restrict__ out) {
  __shared__ Lds L;
  const int blk = blockIdx.x;
  const int t = threadIdx.x;
  unsigned* cnt1 = &sync[0]; unsigned* gen1 = &sync[1];
  unsigned* cnt2 = &sync[2]; unsigned* gen2 = &sync[3];
  unsigned* fpsflag = &sync[4];            // [4],[5] per batch
  unsigned* done2 = &sync[6]; unsigned* chamdone = &sync[7];

  if (blk < 2) {                                       // ---------------- FPS
    fps_body4(L, gt, gtfps, fpsflag, blk);
    return;
  }
  if (blk < 130) {                                     // ---------------- EMD2
    const int eb = blk - 2;
    const int b = eb >> 6, bxl = eb & 63;
    const int r0b = bxl * 64;
    const int iters = *itersPtr;
    const float* fb = fine + (size_t)b*4096*3;
    const float* gb = gt   + (size_t)b*4096*3;
    float* f2b = f2 + b*4096; float* g2b = g2 + b*4096; float* dv2b = dv2 + b*4096;
    for (int ph = 0; ph < 8; ++ph) {
      const int k = ph >> 1;
      if (k < iters) {
        if (!(ph & 1))
          emd_pass_t<8>(fb, 4095, gb, 4095, g2b, f2b, 4096, LOGN2, k > 0, r0b,
                        L.emd.tyx, L.emd.tyy, L.emd.tyz, L.emd.tg);
        else
          emd_pass_t<8>(gb, 4095, fb, 4095, f2b, g2b, 4096, LOGN2, 1, r0b,
                        L.emd.tyx, L.emd.tyy, L.emd.tyz, L.emd.tg);
      }
      gbar(cnt2, gen2, 128u);
    }
    emd_final_t<8>(fb, 4095, gb, 4095, g2b, dv2b, 4096, iters > 0, r0b,
                   L.emd.tyx, L.emd.tyy, L.emd.tyz, L.emd.tg);
    signal_done(done2);
    return;
  }
  // ---------------- EMD1 group: chamfer/copies first, then EMD1, then finalize ----
  {
    const int eb = blk - 130;
    if (eb < 50) {                                     // -------- chamfer (during FPS)
      const int cid = eb;
      const float *q, *tp; float* om; int nq, nt, cb2, qx;
      if (cid < 16)      { cb2 = cid>>3;        qx = cid&7; q = gt;     nq = 4096; tp = coarse; nt = 512;  om = chamA; }
      else if (cid < 18) { cb2 = cid-16;        qx = 0;     q = coarse; nq = 512;  tp = gt;     nt = 4096; om = chamB; }
      else if (cid < 34) { int r = cid-18; cb2 = r>>3; qx = r&7; q = gt;   nq = 4096; tp = fine; nt = 4096; om = chamC; }
      else               { int r = cid-34; cb2 = r>>3; qx = r&7; q = fine; nq = 4096; tp = gt;   nt = 4096; om = chamD; }
      const int qi = qx*512 + t;
      const float* qp = q + (size_t)(cb2*nq + qi)*3;
      float qxv = qp[0], qyv = qp[1], qzv = qp[2];
      float m = 3.4e38f;
      for (int tt0 = 0; tt0 < nt; tt0 += 1024) {
        int chunk = min(1024, nt - tt0);
        __syncthreads();
        for (int i = t; i < chunk; i += 512) {
          const float* pp = tp + (size_t)(cb2*nt + tt0 + i)*3;
          L.ch.x[i] = pp[0]; L.ch.y[i] = pp[1]; L.ch.z[i] = pp[2];
        }
        __syncthreads();
        for (int i = 0; i < chunk; ++i) {
          float dx = qxv-L.ch.x[i], dy = qyv-L.ch.y[i], dz = qzv-L.ch.z[i];
          float d = dx*dx + dy*dy + dz*dz;
          m = fminf(m, d);
        }
      }
      om[cb2*nq + qi] = m;
      signal_done(chamdone);
    } else {                                           // -------- output copies
      for (int i = (eb - 50)*512 + t; i < 27648; i += 14*512)
        out[i] = (i < 3072) ? coarse[i] : fine[i - 3072];
    }
    // -------- EMD1: 64 blocks x 32 rows --------
    const int b = eb >> 5, bxl = eb & 31;
    const int r0b = bxl * 32;
    const int iters = *itersPtr;
    const float* cb = coarse + (size_t)b*512*3;        // xtile == coarse with &511 wrap
    const float* pb = gtfps  + (size_t)b*1024*3;
    float* f1b = f1 + b*1024; float* g1b = g1 + b*1024; float* dv1b = dv1 + b*1024;
    waitcnt_ge(&fpsflag[b], 1u);                       // gtfps ready
    for (int ph = 0; ph < 8; ++ph) {
      const int k = ph >> 1;
      if (k < iters) {
        if (!(ph & 1))
          emd_pass_t<4>(cb, 511, pb, 1023, g1b, f1b, 1024, LOGN1, k > 0, r0b,
                        L.emd.tyx, L.emd.tyy, L.emd.tyz, L.emd.tg);
        else
          emd_pass_t<4>(pb, 1023, cb, 511, f1b, g1b, 1024, LOGN1, 1, r0b,
                        L.emd.tyx, L.emd.tyy, L.emd.tyz, L.emd.tg);
      }
      gbar(cnt1, gen1, 64u);
    }
    emd_final_t<4>(cb, 511, pb, 1023, g1b, dv1b, 1024, iters > 0, r0b,
                   L.emd.tyx, L.emd.tyy, L.emd.tyz, L.emd.tg);
    gbar(cnt1, gen1, 64u);                             // dv1 complete
    if (bxl == 0) {                                    // one finalizer per batch
      waitcnt_ge(done2, 128u);                         // dv2 complete
      waitcnt_ge(chamdone, 50u);                       // chamA-D complete
      finalize_body(b, chamA, chamB, chamC, chamD, dv1, dv2, out, L.emd.tyx);
    }
  }
}

extern "C" void kernel_launch(void* const* d_in, const int* in_sizes, int n_in,
                              void* d_out, int out_size, void* d_ws, size_t ws_size,
                              hipStream_t stream) {
  (void)in_sizes; (void)n_in; (void)out_size; (void)ws_size;
  const float* coarse = (const float*)d_in[0];
  const float* fine   = (const float*)d_in[1];
  const float* gt     = (const float*)d_in[2];
  const int*   iters  = (const int*)d_in[3];
  float* out = (float*)d_out;
  float* ws  = (float*)d_ws;

  float* chamA = ws + 0;        // 2*4096
  float* chamB = ws + 8192;     // 2*512
  float* chamC = ws + 9216;     // 2*4096
  float* chamD = ws + 17408;    // 2*4096
  float* f1    = ws + 25600;    // 2*1024
  float* g1    = ws + 27648;    // 2*1024
  float* dv1   = ws + 29696;    // 2*1024
  float* f2    = ws + 31744;    // 2*4096
  float* g2    = ws + 39936;    // 2*4096
  float* dv2   = ws + 48128;    // 2*4096
  float* gtfps = ws + 56320;    // 2*1024*3
  unsigned* sync = (unsigned*)(ws + 62464);  // 8 words

  init_sync<<<1, 64, 0, stream>>>(sync);
  everything<<<194, 512, 0, stream>>>(coarse, fine, gt, iters,
                                      chamA, chamB, chamC, chamD,
                                      f1, g1, dv1, f2, g2, dv2,
                                      gtfps, sync, out);
}

// Round 10
// 1144.655 us; speedup vs baseline: 1.1850x; 1.1850x over previous
//
#include <hip/hip_runtime.h>
#include <math.h>

static constexpr float EPS_SK = 0.02f;
static constexpr float LOG2E  = 1.4426950408889634f;
static constexpr float LN2F   = 0.6931471805599453f;
#define LOGN1 6.931471805599453f   /* log 1024 */
#define LOGN2 8.317766166719343f   /* log 4096 */

__device__ __forceinline__ float fexp2(float x){ return __builtin_amdgcn_exp2f(x); }
__device__ __forceinline__ float flog2(float x){ return __builtin_amdgcn_logf(x); }

// ============ LDS union padded >80KB => exactly 1 block/CU; 194 blocks co-resident ====
union Lds {
  struct {
    float4 sp[4096];                 // 64 KB points
    float  obx[1024], oby[1024], obz[1024];  // 12 KB selected-point buffer
    unsigned long long sl[2][8];     // parity-double-buffered wave winners
  } fps;
  struct { float tyx[1024], tyy[1024], tyz[1024], tg[1024]; } emd;
  struct { float x[1024], y[1024], z[1024]; } ch;
  float pad[21000];                  // 84000 B -> 1 block/CU
};

// ---------------- sync primitives (validated R5-R9) ----------------
__device__ __forceinline__ void gbar(unsigned* cnt, unsigned* gen, unsigned nblk) {
  __threadfence();
  __syncthreads();
  if (threadIdx.x == 0) {
    unsigned g = __hip_atomic_load(gen, __ATOMIC_ACQUIRE, __HIP_MEMORY_SCOPE_AGENT);
    if (__hip_atomic_fetch_add(cnt, 1u, __ATOMIC_ACQ_REL, __HIP_MEMORY_SCOPE_AGENT) == nblk - 1u) {
      __hip_atomic_store(cnt, 0u, __ATOMIC_RELAXED, __HIP_MEMORY_SCOPE_AGENT);
      __hip_atomic_fetch_add(gen, 1u, __ATOMIC_ACQ_REL, __HIP_MEMORY_SCOPE_AGENT);
    } else {
      while (__hip_atomic_load(gen, __ATOMIC_ACQUIRE, __HIP_MEMORY_SCOPE_AGENT) == g)
        __builtin_amdgcn_s_sleep(8);
    }
  }
  __syncthreads();
  __threadfence();
}

__device__ __forceinline__ void signal_done(unsigned* f) {
  __threadfence();
  __syncthreads();
  if (threadIdx.x == 0)
    __hip_atomic_fetch_add(f, 1u, __ATOMIC_RELEASE, __HIP_MEMORY_SCOPE_AGENT);
}

__device__ __forceinline__ void waitcnt_ge(unsigned* f, unsigned target) {
  if (threadIdx.x == 0)
    while (__hip_atomic_load(f, __ATOMIC_ACQUIRE, __HIP_MEMORY_SCOPE_AGENT) < target)
      __builtin_amdgcn_s_sleep(16);
  __syncthreads();
  __threadfence();
}

// ---- clock-holder: dependent-FMA burn until *f >= tgt (keeps DVFS at load clocks) ----
__device__ __forceinline__ void hold_clock(unsigned* f, unsigned tgt) {
  float a = 1.000001f;
  const float x = 0.9999993f, c = 1e-7f;
  for (;;) {
#pragma unroll 8
    for (int i = 0; i < 512; ++i) a = fmaf(a, x, c);
    asm volatile("" :: "v"(a));   // keep the chain live
    if (__hip_atomic_load(f, __ATOMIC_RELAXED, __HIP_MEMORY_SCOPE_AGENT) >= tgt) break;
  }
}

// DPP-based argmax step: pure VALU cross-lane. max by (value, then smaller idx).
template<int CTRL>
__device__ __forceinline__ void dpp_amax(float& bv, int& bi) {
  float ov = __int_as_float(__builtin_amdgcn_update_dpp(
      __float_as_int(bv), __float_as_int(bv), CTRL, 0xF, 0xF, false));
  int oi = __builtin_amdgcn_update_dpp(bi, bi, CTRL, 0xF, 0xF, false);
  if (ov > bv || (ov == bv && oi < bi)) { bv = ov; bi = oi; }
}

// ---------------- FPS body: 512 threads (8 waves), 8 pts/lane (R5/R6/R7-proven) ------
__device__ __forceinline__ void fps_body(Lds& L, const float* __restrict__ gt,
                                         float* __restrict__ gt_fps, int b) {
  const int t = threadIdx.x;
  const int lane = t & 63;
  const int wv   = t >> 6;
  const float* P = gt + (size_t)b*4096*3;
  for (int i = t; i < 4096; i += 512)
    L.fps.sp[i] = make_float4(P[i*3+0], P[i*3+1], P[i*3+2], 0.0f);
  __syncthreads();
  float px[8], py[8], pz[8], dst[8];
#pragma unroll
  for (int j = 0; j < 8; ++j) {
    float4 q = L.fps.sp[t*8 + j];            // idx = t*8+j (contiguous, j-ascending)
    px[j] = q.x; py[j] = q.y; pz[j] = q.z;
    dst[j] = 1e10f;                          // matches reference init
  }
  float cx, cy, cz;
  { float4 q = L.fps.sp[0]; cx = q.x; cy = q.y; cz = q.z;
    if (t == 0) { L.fps.obx[0] = q.x; L.fps.oby[0] = q.y; L.fps.obz[0] = q.z; } }
  for (int s = 1; s < 1024; ++s) {
    float bv = -1.0f; int bj = 0;
    {
#pragma clang fp contract(off)
#pragma unroll
      for (int j = 0; j < 8; ++j) {
        float dx = px[j]-cx, dy = py[j]-cy, dz = pz[j]-cz;
        float d  = dx*dx + dy*dy + dz*dz;
        float nd = fminf(dst[j], d);
        dst[j] = nd;
        if (nd > bv) { bv = nd; bj = j; }    // strict >, j ascending: first-max kept
      }
    }
    int bi = t*8 + bj;
    dpp_amax<0x111>(bv, bi);  // row_shr:1
    dpp_amax<0x112>(bv, bi);  // row_shr:2
    dpp_amax<0x114>(bv, bi);  // row_shr:4
    dpp_amax<0x118>(bv, bi);  // row_shr:8
    dpp_amax<0x142>(bv, bi);  // row_bcast15
    dpp_amax<0x143>(bv, bi);  // row_bcast31
    const int pb = s & 1;
    if (lane == 63)
      L.fps.sl[pb][wv] = (((unsigned long long)__float_as_uint(bv)) << 32)
                         | (unsigned)(~bi);  // bigger packed = bigger val or smaller idx
    __syncthreads();
    ulonglong2 a0 = *(const ulonglong2*)&L.fps.sl[pb][0];
    ulonglong2 a1 = *(const ulonglong2*)&L.fps.sl[pb][2];
    ulonglong2 a2 = *(const ulonglong2*)&L.fps.sl[pb][4];
    ulonglong2 a3 = *(const ulonglong2*)&L.fps.sl[pb][6];
    unsigned long long bp = a0.x;
    if (a0.y > bp) bp = a0.y;
    if (a1.x > bp) bp = a1.x;
    if (a1.y > bp) bp = a1.y;
    if (a2.x > bp) bp = a2.x;
    if (a2.y > bp) bp = a2.y;
    if (a3.x > bp) bp = a3.x;
    if (a3.y > bp) bp = a3.y;
    int idxw = (int)(~(unsigned)bp);
    float4 c4 = L.fps.sp[idxw];
    cx = c4.x; cy = c4.y; cz = c4.z;
    if (t == 0) { L.fps.obx[s] = c4.x; L.fps.oby[s] = c4.y; L.fps.obz[s] = c4.z; }
  }
  __syncthreads();
  for (int i = t; i < 1024; i += 512) {      // one bulk global store at the end
    float* o = gt_fps + (size_t)(b*1024 + i)*3;
    o[0] = L.fps.obx[i]; o[1] = L.fps.oby[i]; o[2] = L.fps.obz[i];
  }
}

// ============== EMD bodies, 512 threads, JPW rows/wave, masked row wrap (proven) ====
template<int JPW>
__device__ __forceinline__ void emd_pass_t(
    const float* __restrict__ xb, int xm,
    const float* __restrict__ yb, int ym,
    const float* __restrict__ vinb, float* __restrict__ voutb,
    int N, float logN, int use_vin, int r0b,
    float* tyx, float* tyy, float* tyz, float* tg)
{
  const int t = threadIdx.x;
  const int lane = t & 63;
  const int wv   = t >> 6;
  const int r0 = r0b + wv*JPW;
  float px[JPW], py[JPW], pz[JPW], mx[JPW], sm[JPW];
#pragma unroll
  for (int j = 0; j < JPW; ++j) {
    const int row = (r0 + j) & xm;
    const float* xp = xb + (size_t)row*3;
    px[j] = xp[0]; py[j] = xp[1]; pz[j] = xp[2];
    mx[j] = -3.4e38f; sm[j] = 0.0f;
  }
  const float S = LOG2E / EPS_SK;
  const int ntiles = N >> 10;
  for (int tt = 0; tt < ntiles; ++tt) {
    const int base = tt << 10;
    __syncthreads();
    for (int i = t; i < 1024; i += 512) {
      const int row = (base + i) & ym;
      const float* yp = yb + (size_t)row*3;
      tyx[i] = yp[0]; tyy[i] = yp[1]; tyz[i] = yp[2];
      tg[i]  = use_vin ? vinb[base + i] : 0.0f;
    }
    __syncthreads();
    for (int mi = lane; mi < 1024; mi += 64) {
      float yx = tyx[mi], yy = tyy[mi], yz = tyz[mi], g = tg[mi];
#pragma unroll
      for (int j = 0; j < JPW; ++j) {
        float dx = px[j]-yx, dy = py[j]-yy, dz = pz[j]-yz;
        float d  = dx*dx + dy*dy + dz*dz;
        float tv = (g - d) * S;
        float nm = fmaxf(mx[j], tv);
        sm[j] = sm[j]*fexp2(mx[j]-nm) + fexp2(tv-nm);
        mx[j] = nm;
      }
    }
  }
#pragma unroll
  for (int j = 0; j < JPW; ++j) {
#pragma unroll
    for (int off = 1; off < 64; off <<= 1) {
      float om = __shfl_xor(mx[j], off, 64);
      float os = __shfl_xor(sm[j], off, 64);
      float nm = fmaxf(mx[j], om);
      sm[j] = sm[j]*fexp2(mx[j]-nm) + os*fexp2(om-nm);
      mx[j] = nm;
    }
  }
  if (lane == 0) {
#pragma unroll
    for (int j = 0; j < JPW; ++j) {
      float lse = (mx[j] + flog2(sm[j])) * LN2F;
      voutb[r0 + j] = -EPS_SK * (lse + logN);
    }
  }
}

template<int JPW>
__device__ __forceinline__ void emd_final_t(
    const float* __restrict__ xb, int xm,
    const float* __restrict__ yb, int ym,
    const float* __restrict__ ginb, float* __restrict__ doutb,
    int N, int use_g, int r0b,
    float* tyx, float* tyy, float* tyz, float* tg)
{
  const int t = threadIdx.x;
  const int lane = t & 63;
  const int wv   = t >> 6;
  const int r0 = r0b + wv*JPW;
  float px[JPW], py[JPW], pz[JPW], mx[JPW], sm[JPW], wc[JPW];
#pragma unroll
  for (int j = 0; j < JPW; ++j) {
    const int row = (r0 + j) & xm;
    const float* xp = xb + (size_t)row*3;
    px[j] = xp[0]; py[j] = xp[1]; pz[j] = xp[2];
    mx[j] = -3.4e38f; sm[j] = 0.0f; wc[j] = 0.0f;
  }
  const float S = LOG2E / EPS_SK;
  const int ntiles = N >> 10;
  for (int tt = 0; tt < ntiles; ++tt) {
    const int base = tt << 10;
    __syncthreads();
    for (int i = t; i < 1024; i += 512) {
      const int row = (base + i) & ym;
      const float* yp = yb + (size_t)row*3;
      tyx[i] = yp[0]; tyy[i] = yp[1]; tyz[i] = yp[2];
      tg[i]  = use_g ? ginb[base + i] : 0.0f;
    }
    __syncthreads();
    for (int mi = lane; mi < 1024; mi += 64) {
      float yx = tyx[mi], yy = tyy[mi], yz = tyz[mi], g = tg[mi];
#pragma unroll
      for (int j = 0; j < JPW; ++j) {
        float dx = px[j]-yx, dy = py[j]-yy, dz = pz[j]-yz;
        float d  = dx*dx + dy*dy + dz*dz;
        float tv = (g - d) * S;
        float nm = fmaxf(mx[j], tv);
        float r  = fexp2(mx[j]-nm);
        float e  = fexp2(tv-nm);
        sm[j] = sm[j]*r + e;
        wc[j] = wc[j]*r + e*d;
        mx[j] = nm;
      }
    }
  }
#pragma unroll
  for (int j = 0; j < JPW; ++j) {
#pragma unroll
    for (int off = 1; off < 64; off <<= 1) {
      float om = __shfl_xor(mx[j], off, 64);
      float os = __shfl_xor(sm[j], off, 64);
      float ow = __shfl_xor(wc[j], off, 64);
      float nm = fmaxf(mx[j], om);
      float r1 = fexp2(mx[j]-nm);
      float r2 = fexp2(om-nm);
      sm[j] = sm[j]*r1 + os*r2;
      wc[j] = wc[j]*r1 + ow*r2;
      mx[j] = nm;
    }
  }
  if (lane == 0) {
#pragma unroll
    for (int j = 0; j < JPW; ++j)
      doutb[r0 + j] = sqrtf(wc[j] / sm[j]);
  }
}

__device__ __forceinline__ float blk_sum512(float v, float* lds) {
#pragma unroll
  for (int off = 32; off >= 1; off >>= 1) v += __shfl_xor(v, off, 64);
  int lane = threadIdx.x & 63, wv = threadIdx.x >> 6;
  __syncthreads();
  if (lane == 0) lds[wv] = v;
  __syncthreads();
  return lds[0]+lds[1]+lds[2]+lds[3]+lds[4]+lds[5]+lds[6]+lds[7];
}

__device__ __forceinline__ void finalize_body(int b,
    const float* __restrict__ A, const float* __restrict__ B,
    const float* __restrict__ C, const float* __restrict__ D,
    const float* __restrict__ dv1, const float* __restrict__ dv2,
    float* __restrict__ out, float* lds) {
  const int t = threadIdx.x;
  float e1 = 0, e2 = 0;
  for (int i = t; i < 1024; i += 512) e1 += dv1[b*1024+i];
  e1 = blk_sum512(e1, lds);
  for (int i = t; i < 4096; i += 512) e2 += dv2[b*4096+i];
  e2 = blk_sum512(e2, lds);
  float rA=0, sA=0, rB=0, sB=0, rC=0, sC=0, rD=0, sD=0;
  for (int i = t; i < 4096; i += 512) { float v = A[b*4096+i]; rA += v; sA += sqrtf(v); }
  rA = blk_sum512(rA, lds); sA = blk_sum512(sA, lds);
  for (int i = t; i < 512;  i += 512) { float v = B[b*512+i];  rB += v; sB += sqrtf(v); }
  rB = blk_sum512(rB, lds); sB = blk_sum512(sB, lds);
  for (int i = t; i < 4096; i += 512) { float v = C[b*4096+i]; rC += v; sC += sqrtf(v); }
  rC = blk_sum512(rC, lds); sC = blk_sum512(sC, lds);
  for (int i = t; i < 4096; i += 512) { float v = D[b*4096+i]; rD += v; sD += sqrtf(v); }
  rD = blk_sum512(rD, lds); sD = blk_sum512(sD, lds);
  if (t == 0) {
    out[27648 + b] = e1 / 1024.0f;
    out[27650 + b] = e2 / 4096.0f;
    out[27652 + b] = 0.5f*(sA/4096.0f + sB/512.0f);
    out[27654 + b] = 0.5f*(sC/4096.0f + sD/4096.0f);
    out[27656 + b] = rA/4096.0f + rB/512.0f;
    out[27658 + b] = rC/4096.0f + rD/4096.0f;
  }
}

// ---- tiny init: zero the 16 sync words (replay-safe) ----
__global__ void init_sync(unsigned* __restrict__ sync) {
  if (threadIdx.x < 16)
    __hip_atomic_store(&sync[threadIdx.x], 0u, __ATOMIC_RELAXED, __HIP_MEMORY_SCOPE_AGENT);
}

// ===================== the one big kernel: 194 blocks x 512 ====================
// blk 0-1: FPS | blk 2-129: EMD2 then CLOCK-HOLD until EMD1 done
// blk 130-193: chamfer(50)/copies(14) first, then EMD1 (64 blocks x 32 rows), finalize
__global__ __launch_bounds__(512) void everything(
    const float* __restrict__ coarse, const float* __restrict__ fine,
    const float* __restrict__ gt, const int* __restrict__ itersPtr,
    float* __restrict__ chamA, float* __restrict__ chamB,
    float* __restrict__ chamC, float* __restrict__ chamD,
    float* __restrict__ f1, float* __restrict__ g1, float* __restrict__ dv1,
    float* __restrict__ f2, float* __restrict__ g2, float* __restrict__ dv2,
    float* __restrict__ gtfps, unsigned* __restrict__ sync,
    float* __restrict__ out) {
  __shared__ Lds L;
  const int blk = blockIdx.x;
  const int t = threadIdx.x;
  unsigned* cnt1 = &sync[0]; unsigned* gen1 = &sync[1];
  unsigned* cnt2 = &sync[2]; unsigned* gen2 = &sync[3];
  unsigned* fpsflag = &sync[4];            // [4],[5] per batch
  unsigned* done2 = &sync[6]; unsigned* chamdone = &sync[7];
  unsigned* done1 = &sync[8];

  if (blk < 2) {                                       // ---------------- FPS
    fps_body(L, gt, gtfps, blk);
    signal_done(&fpsflag[blk]);
    return;
  }
  if (blk < 130) {                                     // ---------------- EMD2
    const int eb = blk - 2;
    const int b = eb >> 6, bxl = eb & 63;
    const int r0b = bxl * 64;
    const int iters = *itersPtr;
    const float* fb = fine + (size_t)b*4096*3;
    const float* gb = gt   + (size_t)b*4096*3;
    float* f2b = f2 + b*4096; float* g2b = g2 + b*4096; float* dv2b = dv2 + b*4096;
    for (int ph = 0; ph < 8; ++ph) {
      const int k = ph >> 1;
      if (k < iters) {
        if (!(ph & 1))
          emd_pass_t<8>(fb, 4095, gb, 4095, g2b, f2b, 4096, LOGN2, k > 0, r0b,
                        L.emd.tyx, L.emd.tyy, L.emd.tyz, L.emd.tg);
        else
          emd_pass_t<8>(gb, 4095, fb, 4095, f2b, g2b, 4096, LOGN2, 1, r0b,
                        L.emd.tyx, L.emd.tyy, L.emd.tyz, L.emd.tg);
      }
      gbar(cnt2, gen2, 128u);
    }
    emd_final_t<8>(fb, 4095, gb, 4095, g2b, dv2b, 4096, iters > 0, r0b,
                   L.emd.tyx, L.emd.tyy, L.emd.tyz, L.emd.tg);
    signal_done(done2);
    hold_clock(done1, 64u);                            // keep DVFS up through FPS+EMD1
    return;
  }
  // ---------------- EMD1 group: chamfer/copies first, then EMD1, then finalize ----
  {
    const int eb = blk - 130;
    if (eb < 50) {                                     // -------- chamfer (during FPS)
      const int cid = eb;
      const float *q, *tp; float* om; int nq, nt, cb2, qx;
      if (cid < 16)      { cb2 = cid>>3;        qx = cid&7; q = gt;     nq = 4096; tp = coarse; nt = 512;  om = chamA; }
      else if (cid < 18) { cb2 = cid-16;        qx = 0;     q = coarse; nq = 512;  tp = gt;     nt = 4096; om = chamB; }
      else if (cid < 34) { int r = cid-18; cb2 = r>>3; qx = r&7; q = gt;   nq = 4096; tp = fine; nt = 4096; om = chamC; }
      else               { int r = cid-34; cb2 = r>>3; qx = r&7; q = fine; nq = 4096; tp = gt;   nt = 4096; om = chamD; }
      const int qi = qx*512 + t;
      const float* qp = q + (size_t)(cb2*nq + qi)*3;
      float qxv = qp[0], qyv = qp[1], qzv = qp[2];
      float m = 3.4e38f;
      for (int tt0 = 0; tt0 < nt; tt0 += 1024) {
        int chunk = min(1024, nt - tt0);
        __syncthreads();
        for (int i = t; i < chunk; i += 512) {
          const float* pp = tp + (size_t)(cb2*nt + tt0 + i)*3;
          L.ch.x[i] = pp[0]; L.ch.y[i] = pp[1]; L.ch.z[i] = pp[2];
        }
        __syncthreads();
        for (int i = 0; i < chunk; ++i) {
          float dx = qxv-L.ch.x[i], dy = qyv-L.ch.y[i], dz = qzv-L.ch.z[i];
          float d = dx*dx + dy*dy + dz*dz;
          m = fminf(m, d);
        }
      }
      om[cb2*nq + qi] = m;
      signal_done(chamdone);
    } else {                                           // -------- output copies
      for (int i = (eb - 50)*512 + t; i < 27648; i += 14*512)
        out[i] = (i < 3072) ? coarse[i] : fine[i - 3072];
    }
    // -------- EMD1: 64 blocks x 32 rows --------
    const int b = eb >> 5, bxl = eb & 31;
    const int r0b = bxl * 32;
    const int iters = *itersPtr;
    const float* cb = coarse + (size_t)b*512*3;        // xtile == coarse with &511 wrap
    const float* pb = gtfps  + (size_t)b*1024*3;
    float* f1b = f1 + b*1024; float* g1b = g1 + b*1024; float* dv1b = dv1 + b*1024;
    waitcnt_ge(&fpsflag[b], 1u);                       // gtfps ready
    for (int ph = 0; ph < 8; ++ph) {
      const int k = ph >> 1;
      if (k < iters) {
        if (!(ph & 1))
          emd_pass_t<4>(cb, 511, pb, 1023, g1b, f1b, 1024, LOGN1, k > 0, r0b,
                        L.emd.tyx, L.emd.tyy, L.emd.tyz, L.emd.tg);
        else
          emd_pass_t<4>(pb, 1023, cb, 511, f1b, g1b, 1024, LOGN1, 1, r0b,
                        L.emd.tyx, L.emd.tyy, L.emd.tyz, L.emd.tg);
      }
      gbar(cnt1, gen1, 64u);
    }
    emd_final_t<4>(cb, 511, pb, 1023, g1b, dv1b, 1024, iters > 0, r0b,
                   L.emd.tyx, L.emd.tyy, L.emd.tyz, L.emd.tg);
    gbar(cnt1, gen1, 64u);                             // dv1 complete
    signal_done(done1);                                // releases the clock-holders
    if (bxl == 0) {                                    // one finalizer per batch
      waitcnt_ge(done2, 128u);                         // dv2 complete
      waitcnt_ge(chamdone, 50u);                       // chamA-D complete
      finalize_body(b, chamA, chamB, chamC, chamD, dv1, dv2, out, L.emd.tyx);
    }
  }
}

extern "C" void kernel_launch(void* const* d_in, const int* in_sizes, int n_in,
                              void* d_out, int out_size, void* d_ws, size_t ws_size,
                              hipStream_t stream) {
  (void)in_sizes; (void)n_in; (void)out_size; (void)ws_size;
  const float* coarse = (const float*)d_in[0];
  const float* fine   = (const float*)d_in[1];
  const float* gt     = (const float*)d_in[2];
  const int*   iters  = (const int*)d_in[3];
  float* out = (float*)d_out;
  float* ws  = (float*)d_ws;

  float* chamA = ws + 0;        // 2*4096
  float* chamB = ws + 8192;     // 2*512
  float* chamC = ws + 9216;     // 2*4096
  float* chamD = ws + 17408;    // 2*4096
  float* f1    = ws + 25600;    // 2*1024
  float* g1    = ws + 27648;    // 2*1024
  float* dv1   = ws + 29696;    // 2*1024
  float* f2    = ws + 31744;    // 2*4096
  float* g2    = ws + 39936;    // 2*4096
  float* dv2   = ws + 48128;    // 2*4096
  float* gtfps = ws + 56320;    // 2*1024*3
  unsigned* sync = (unsigned*)(ws + 62464);  // 16 words

  init_sync<<<1, 64, 0, stream>>>(sync);
  everything<<<194, 512, 0, stream>>>(coarse, fine, gt, iters,
                                      chamA, chamB, chamC, chamD,
                                      f1, g1, dv1, f2, g2, dv2,
                                      gtfps, sync, out);
}

// Round 11
// 1014.148 us; speedup vs baseline: 1.3375x; 1.1287x over previous
//
#include <hip/hip_runtime.h>
#include <math.h>

static constexpr float EPS_SK = 0.02f;
static constexpr float LOG2E  = 1.4426950408889634f;
static constexpr float LN2F   = 0.6931471805599453f;
#define LOGN1 6.931471805599453f   /* log 1024 */
#define LOGN2 8.317766166719343f   /* log 4096 */

__device__ __forceinline__ float fexp2(float x){ return __builtin_amdgcn_exp2f(x); }
__device__ __forceinline__ float flog2(float x){ return __builtin_amdgcn_logf(x); }

using f32x2 = __attribute__((ext_vector_type(2))) float;

// ============ LDS union padded >80KB => exactly 1 block/CU; 194 blocks co-resident ====
union Lds {
  struct {
    float sx[4096], sy[4096], sz[4096];      // 48 KB staged points (SoA for pk loads)
    float obx[1024], oby[1024], obz[1024];   // 12 KB selected-point buffer
    unsigned long long sl[2][8];             // parity-double-buffered wave winners
  } fps;
  struct { float tyx[1024], tyy[1024], tyz[1024], tg[1024]; } emd;
  struct { float x[1024], y[1024], z[1024]; } ch;
  float pad[21000];                          // 84000 B -> 1 block/CU
};

// ---------------- sync primitives (validated R5-R10) ----------------
__device__ __forceinline__ void gbar(unsigned* cnt, unsigned* gen, unsigned nblk) {
  __threadfence();
  __syncthreads();
  if (threadIdx.x == 0) {
    unsigned g = __hip_atomic_load(gen, __ATOMIC_ACQUIRE, __HIP_MEMORY_SCOPE_AGENT);
    if (__hip_atomic_fetch_add(cnt, 1u, __ATOMIC_ACQ_REL, __HIP_MEMORY_SCOPE_AGENT) == nblk - 1u) {
      __hip_atomic_store(cnt, 0u, __ATOMIC_RELAXED, __HIP_MEMORY_SCOPE_AGENT);
      __hip_atomic_fetch_add(gen, 1u, __ATOMIC_ACQ_REL, __HIP_MEMORY_SCOPE_AGENT);
    } else {
      while (__hip_atomic_load(gen, __ATOMIC_ACQUIRE, __HIP_MEMORY_SCOPE_AGENT) == g)
        __builtin_amdgcn_s_sleep(8);
    }
  }
  __syncthreads();
  __threadfence();
}

__device__ __forceinline__ void signal_done(unsigned* f) {
  __threadfence();
  __syncthreads();
  if (threadIdx.x == 0)
    __hip_atomic_fetch_add(f, 1u, __ATOMIC_RELEASE, __HIP_MEMORY_SCOPE_AGENT);
}

__device__ __forceinline__ void waitcnt_ge(unsigned* f, unsigned target) {
  if (threadIdx.x == 0)
    while (__hip_atomic_load(f, __ATOMIC_ACQUIRE, __HIP_MEMORY_SCOPE_AGENT) < target)
      __builtin_amdgcn_s_sleep(16);
  __syncthreads();
  __threadfence();
}

// DPP helpers (old=self => invalid lanes are no-ops); chains accumulate to lane 63
template<int C>
__device__ __forceinline__ float dppf(float x) {
  return __int_as_float(__builtin_amdgcn_update_dpp(
      __float_as_int(x), __float_as_int(x), C, 0xF, 0xF, false));
}
template<int C>
__device__ __forceinline__ int dppi(int x) {
  return __builtin_amdgcn_update_dpp(x, x, C, 0xF, 0xF, false);
}
__device__ __forceinline__ float wave_max_to_l63(float v) {
  v = fmaxf(v, dppf<0x111>(v));  // row_shr:1
  v = fmaxf(v, dppf<0x112>(v));  // row_shr:2
  v = fmaxf(v, dppf<0x114>(v));  // row_shr:4
  v = fmaxf(v, dppf<0x118>(v));  // row_shr:8
  v = fmaxf(v, dppf<0x142>(v));  // row_bcast15
  v = fmaxf(v, dppf<0x143>(v));  // row_bcast31
  return v;
}
__device__ __forceinline__ int wave_min_to_l63(int v) {
  v = min(v, dppi<0x111>(v));
  v = min(v, dppi<0x112>(v));
  v = min(v, dppi<0x114>(v));
  v = min(v, dppi<0x118>(v));
  v = min(v, dppi<0x142>(v));
  v = min(v, dppi<0x143>(v));
  return v;
}
__device__ __forceinline__ unsigned long long u64max(unsigned long long a, unsigned long long b) {
  return a > b ? a : b;
}

// ---------------- FPS body: 512 threads (8 waves), 8 pts/lane as 4 f32x2 pairs ------
// pk distance update + value-only DPP max + exact-scan index + DPP min-index.
// Exchange: u64 slot (val<<32 | ~idx), parity double-buffered, one barrier/iter.
__device__ __forceinline__ void fps_body(Lds& L, const float* __restrict__ gt,
                                         float* __restrict__ gt_fps, int b) {
  const int t = threadIdx.x;
  const int lane = t & 63;
  const int wv   = t >> 6;
  const float* P = gt + (size_t)b*4096*3;
  for (int i = t; i < 4096; i += 512) {
    L.fps.sx[i] = P[i*3+0]; L.fps.sy[i] = P[i*3+1]; L.fps.sz[i] = P[i*3+2];
  }
  __syncthreads();
  // global idx = t*8 + 2*p + half  (ascending in (p, half) for fixed t)
  f32x2 px[4], py[4], pz[4], d2[4];
#pragma unroll
  for (int p = 0; p < 4; ++p) {
    const int i0 = t*8 + 2*p;
    px[p] = *(const f32x2*)&L.fps.sx[i0];
    py[p] = *(const f32x2*)&L.fps.sy[i0];
    pz[p] = *(const f32x2*)&L.fps.sz[i0];
    d2[p].x = 1e10f; d2[p].y = 1e10f;        // matches reference init
  }
  float cx = L.fps.sx[0], cy = L.fps.sy[0], cz = L.fps.sz[0];
  if (t == 0) { L.fps.obx[0] = cx; L.fps.oby[0] = cy; L.fps.obz[0] = cz; }
  for (int s = 1; s < 1024; ++s) {
    f32x2 bv2; bv2.x = -1.0f; bv2.y = -1.0f;
    {
#pragma clang fp contract(off)
      f32x2 c2x; c2x.x = cx; c2x.y = cx;
      f32x2 c2y; c2y.x = cy; c2y.y = cy;
      f32x2 c2z; c2z.x = cz; c2z.y = cz;
#pragma unroll
      for (int p = 0; p < 4; ++p) {
        f32x2 dx = px[p]-c2x, dy = py[p]-c2y, dz = pz[p]-c2z;
        f32x2 d  = dx*dx + dy*dy + dz*dz;    // pk mul/add, IEEE-exact per half
        f32x2 nd = __builtin_elementwise_min(d2[p], d);
        d2[p] = nd;
        bv2 = __builtin_elementwise_max(bv2, nd);
      }
    }
    float bv = fmaxf(bv2.x, bv2.y);
    bv = wave_max_to_l63(bv);
    const unsigned Mbits = (unsigned)__builtin_amdgcn_readlane(__float_as_int(bv), 63);
    const float M = __uint_as_float(Mbits);
    // exact-compare scan; min matching global idx == first occurrence (R9-proven)
    int ic = 0x7FFFFFFF;
#pragma unroll
    for (int p = 0; p < 4; ++p) {
      const int i0 = t*8 + 2*p;
      if (d2[p].x == M) ic = min(ic, i0);
      if (d2[p].y == M) ic = min(ic, i0 + 1);
    }
    ic = wave_min_to_l63(ic);
    const int widx = __builtin_amdgcn_readlane(ic, 63);   // SGPR-uniform
    const int pb = s & 1;
    if (lane == 0)
      L.fps.sl[pb][wv] = (((unsigned long long)Mbits) << 32)
                         | (unsigned)(~widx); // bigger packed = bigger val or smaller idx
    __syncthreads();
    ulonglong2 a0 = *(const ulonglong2*)&L.fps.sl[pb][0];
    ulonglong2 a1 = *(const ulonglong2*)&L.fps.sl[pb][2];
    ulonglong2 a2 = *(const ulonglong2*)&L.fps.sl[pb][4];
    ulonglong2 a3 = *(const ulonglong2*)&L.fps.sl[pb][6];
    // 3-level tree (shorter dep chain than serial 7-compare)
    unsigned long long m0 = u64max(a0.x, a0.y);
    unsigned long long m1 = u64max(a1.x, a1.y);
    unsigned long long m2 = u64max(a2.x, a2.y);
    unsigned long long m3 = u64max(a3.x, a3.y);
    unsigned long long bp = u64max(u64max(m0, m1), u64max(m2, m3));
    int idxw = (int)(~(unsigned)bp);
    cx = L.fps.sx[idxw]; cy = L.fps.sy[idxw]; cz = L.fps.sz[idxw];  // broadcast reads
    if (t == 0) { L.fps.obx[s] = cx; L.fps.oby[s] = cy; L.fps.obz[s] = cz; }
  }
  __syncthreads();
  for (int i = t; i < 1024; i += 512) {      // one bulk global store at the end
    float* o = gt_fps + (size_t)(b*1024 + i)*3;
    o[0] = L.fps.obx[i]; o[1] = L.fps.oby[i]; o[2] = L.fps.obz[i];
  }
}

// ============== EMD bodies, 512 threads, JPW rows/wave, masked row wrap (proven) ====
template<int JPW>
__device__ __forceinline__ void emd_pass_t(
    const float* __restrict__ xb, int xm,
    const float* __restrict__ yb, int ym,
    const float* __restrict__ vinb, float* __restrict__ voutb,
    int N, float logN, int use_vin, int r0b,
    float* tyx, float* tyy, float* tyz, float* tg)
{
  const int t = threadIdx.x;
  const int lane = t & 63;
  const int wv   = t >> 6;
  const int r0 = r0b + wv*JPW;
  float px[JPW], py[JPW], pz[JPW], mx[JPW], sm[JPW];
#pragma unroll
  for (int j = 0; j < JPW; ++j) {
    const int row = (r0 + j) & xm;
    const float* xp = xb + (size_t)row*3;
    px[j] = xp[0]; py[j] = xp[1]; pz[j] = xp[2];
    mx[j] = -3.4e38f; sm[j] = 0.0f;
  }
  const float S = LOG2E / EPS_SK;
  const int ntiles = N >> 10;
  for (int tt = 0; tt < ntiles; ++tt) {
    const int base = tt << 10;
    __syncthreads();
    for (int i = t; i < 1024; i += 512) {
      const int row = (base + i) & ym;
      const float* yp = yb + (size_t)row*3;
      tyx[i] = yp[0]; tyy[i] = yp[1]; tyz[i] = yp[2];
      tg[i]  = use_vin ? vinb[base + i] : 0.0f;
    }
    __syncthreads();
    for (int mi = lane; mi < 1024; mi += 64) {
      float yx = tyx[mi], yy = tyy[mi], yz = tyz[mi], g = tg[mi];
#pragma unroll
      for (int j = 0; j < JPW; ++j) {
        float dx = px[j]-yx, dy = py[j]-yy, dz = pz[j]-yz;
        float d  = dx*dx + dy*dy + dz*dz;
        float tv = (g - d) * S;
        float nm = fmaxf(mx[j], tv);
        sm[j] = sm[j]*fexp2(mx[j]-nm) + fexp2(tv-nm);
        mx[j] = nm;
      }
    }
  }
#pragma unroll
  for (int j = 0; j < JPW; ++j) {
#pragma unroll
    for (int off = 1; off < 64; off <<= 1) {
      float om = __shfl_xor(mx[j], off, 64);
      float os = __shfl_xor(sm[j], off, 64);
      float nm = fmaxf(mx[j], om);
      sm[j] = sm[j]*fexp2(mx[j]-nm) + os*fexp2(om-nm);
      mx[j] = nm;
    }
  }
  if (lane == 0) {
#pragma unroll
    for (int j = 0; j < JPW; ++j) {
      float lse = (mx[j] + flog2(sm[j])) * LN2F;
      voutb[r0 + j] = -EPS_SK * (lse + logN);
    }
  }
}

template<int JPW>
__device__ __forceinline__ void emd_final_t(
    const float* __restrict__ xb, int xm,
    const float* __restrict__ yb, int ym,
    const float* __restrict__ ginb, float* __restrict__ doutb,
    int N, int use_g, int r0b,
    float* tyx, float* tyy, float* tyz, float* tg)
{
  const int t = threadIdx.x;
  const int lane = t & 63;
  const int wv   = t >> 6;
  const int r0 = r0b + wv*JPW;
  float px[JPW], py[JPW], pz[JPW], mx[JPW], sm[JPW], wc[JPW];
#pragma unroll
  for (int j = 0; j < JPW; ++j) {
    const int row = (r0 + j) & xm;
    const float* xp = xb + (size_t)row*3;
    px[j] = xp[0]; py[j] = xp[1]; pz[j] = xp[2];
    mx[j] = -3.4e38f; sm[j] = 0.0f; wc[j] = 0.0f;
  }
  const float S = LOG2E / EPS_SK;
  const int ntiles = N >> 10;
  for (int tt = 0; tt < ntiles; ++tt) {
    const int base = tt << 10;
    __syncthreads();
    for (int i = t; i < 1024; i += 512) {
      const int row = (base + i) & ym;
      const float* yp = yb + (size_t)row*3;
      tyx[i] = yp[0]; tyy[i] = yp[1]; tyz[i] = yp[2];
      tg[i]  = use_g ? ginb[base + i] : 0.0f;
    }
    __syncthreads();
    for (int mi = lane; mi < 1024; mi += 64) {
      float yx = tyx[mi], yy = tyy[mi], yz = tyz[mi], g = tg[mi];
#pragma unroll
      for (int j = 0; j < JPW; ++j) {
        float dx = px[j]-yx, dy = py[j]-yy, dz = pz[j]-yz;
        float d  = dx*dx + dy*dy + dz*dz;
        float tv = (g - d) * S;
        float nm = fmaxf(mx[j], tv);
        float r  = fexp2(mx[j]-nm);
        float e  = fexp2(tv-nm);
        sm[j] = sm[j]*r + e;
        wc[j] = wc[j]*r + e*d;
        mx[j] = nm;
      }
    }
  }
#pragma unroll
  for (int j = 0; j < JPW; ++j) {
#pragma unroll
    for (int off = 1; off < 64; off <<= 1) {
      float om = __shfl_xor(mx[j], off, 64);
      float os = __shfl_xor(sm[j], off, 64);
      float ow = __shfl_xor(wc[j], off, 64);
      float nm = fmaxf(mx[j], om);
      float r1 = fexp2(mx[j]-nm);
      float r2 = fexp2(om-nm);
      sm[j] = sm[j]*r1 + os*r2;
      wc[j] = wc[j]*r1 + ow*r2;
      mx[j] = nm;
    }
  }
  if (lane == 0) {
#pragma unroll
    for (int j = 0; j < JPW; ++j)
      doutb[r0 + j] = sqrtf(wc[j] / sm[j]);
  }
}

__device__ __forceinline__ float blk_sum512(float v, float* lds) {
#pragma unroll
  for (int off = 32; off >= 1; off >>= 1) v += __shfl_xor(v, off, 64);
  int lane = threadIdx.x & 63, wv = threadIdx.x >> 6;
  __syncthreads();
  if (lane == 0) lds[wv] = v;
  __syncthreads();
  return lds[0]+lds[1]+lds[2]+lds[3]+lds[4]+lds[5]+lds[6]+lds[7];
}

__device__ __forceinline__ void finalize_body(int b,
    const float* __restrict__ A, const float* __restrict__ B,
    const float* __restrict__ C, const float* __restrict__ D,
    const float* __restrict__ dv1, const float* __restrict__ dv2,
    float* __restrict__ out, float* lds) {
  const int t = threadIdx.x;
  float e1 = 0, e2 = 0;
  for (int i = t; i < 1024; i += 512) e1 += dv1[b*1024+i];
  e1 = blk_sum512(e1, lds);
  for (int i = t; i < 4096; i += 512) e2 += dv2[b*4096+i];
  e2 = blk_sum512(e2, lds);
  float rA=0, sA=0, rB=0, sB=0, rC=0, sC=0, rD=0, sD=0;
  for (int i = t; i < 4096; i += 512) { float v = A[b*4096+i]; rA += v; sA += sqrtf(v); }
  rA = blk_sum512(rA, lds); sA = blk_sum512(sA, lds);
  for (int i = t; i < 512;  i += 512) { float v = B[b*512+i];  rB += v; sB += sqrtf(v); }
  rB = blk_sum512(rB, lds); sB = blk_sum512(sB, lds);
  for (int i = t; i < 4096; i += 512) { float v = C[b*4096+i]; rC += v; sC += sqrtf(v); }
  rC = blk_sum512(rC, lds); sC = blk_sum512(sC, lds);
  for (int i = t; i < 4096; i += 512) { float v = D[b*4096+i]; rD += v; sD += sqrtf(v); }
  rD = blk_sum512(rD, lds); sD = blk_sum512(sD, lds);
  if (t == 0) {
    out[27648 + b] = e1 / 1024.0f;
    out[27650 + b] = e2 / 4096.0f;
    out[27652 + b] = 0.5f*(sA/4096.0f + sB/512.0f);
    out[27654 + b] = 0.5f*(sC/4096.0f + sD/4096.0f);
    out[27656 + b] = rA/4096.0f + rB/512.0f;
    out[27658 + b] = rC/4096.0f + rD/4096.0f;
  }
}

// ---- tiny init: zero the 8 sync words (replay-safe) ----
__global__ void init_sync(unsigned* __restrict__ sync) {
  if (threadIdx.x < 8)
    __hip_atomic_store(&sync[threadIdx.x], 0u, __ATOMIC_RELAXED, __HIP_MEMORY_SCOPE_AGENT);
}

// ===================== the one big kernel: 194 blocks x 512 ====================
// blk 0-1: FPS | blk 2-129: EMD2 persistent (128 x 64 rows)
// blk 130-193: chamfer(50)/copies(14) first, then EMD1 (64 x 32 rows), finalize
__global__ __launch_bounds__(512) void everything(
    const float* __restrict__ coarse, const float* __restrict__ fine,
    const float* __restrict__ gt, const int* __restrict__ itersPtr,
    float* __restrict__ chamA, float* __restrict__ chamB,
    float* __restrict__ chamC, float* __restrict__ chamD,
    float* __restrict__ f1, float* __restrict__ g1, float* __restrict__ dv1,
    float* __restrict__ f2, float* __restrict__ g2, float* __restrict__ dv2,
    float* __restrict__ gtfps, unsigned* __restrict__ sync,
    float* __restrict__ out) {
  __shared__ Lds L;
  const int blk = blockIdx.x;
  const int t = threadIdx.x;
  unsigned* cnt1 = &sync[0]; unsigned* gen1 = &sync[1];
  unsigned* cnt2 = &sync[2]; unsigned* gen2 = &sync[3];
  unsigned* fpsflag = &sync[4];            // [4],[5] per batch
  unsigned* done2 = &sync[6]; unsigned* chamdone = &sync[7];

  if (blk < 2) {                                       // ---------------- FPS
    fps_body(L, gt, gtfps, blk);
    signal_done(&fpsflag[blk]);
    return;
  }
  if (blk < 130) {                                     // ---------------- EMD2
    const int eb = blk - 2;
    const int b = eb >> 6, bxl = eb & 63;
    const int r0b = bxl * 64;
    const int iters = *itersPtr;
    const float* fb = fine + (size_t)b*4096*3;
    const float* gb = gt   + (size_t)b*4096*3;
    float* f2b = f2 + b*4096; float* g2b = g2 + b*4096; float* dv2b = dv2 + b*4096;
    for (int ph = 0; ph < 8; ++ph) {
      const int k = ph >> 1;
      if (k < iters) {
        if (!(ph & 1))
          emd_pass_t<8>(fb, 4095, gb, 4095, g2b, f2b, 4096, LOGN2, k > 0, r0b,
                        L.emd.tyx, L.emd.tyy, L.emd.tyz, L.emd.tg);
        else
          emd_pass_t<8>(gb, 4095, fb, 4095, f2b, g2b, 4096, LOGN2, 1, r0b,
                        L.emd.tyx, L.emd.tyy, L.emd.tyz, L.emd.tg);
      }
      gbar(cnt2, gen2, 128u);
    }
    emd_final_t<8>(fb, 4095, gb, 4095, g2b, dv2b, 4096, iters > 0, r0b,
                   L.emd.tyx, L.emd.tyy, L.emd.tyz, L.emd.tg);
    signal_done(done2);
    return;
  }
  // ---------------- EMD1 group: chamfer/copies first, then EMD1, then finalize ----
  {
    const int eb = blk - 130;
    if (eb < 50) {                                     // -------- chamfer (during FPS)
      const int cid = eb;
      const float *q, *tp; float* om; int nq, nt, cb2, qx;
      if (cid < 16)      { cb2 = cid>>3;        qx = cid&7; q = gt;     nq = 4096; tp = coarse; nt = 512;  om = chamA; }
      else if (cid < 18) { cb2 = cid-16;        qx = 0;     q = coarse; nq = 512;  tp = gt;     nt = 4096; om = chamB; }
      else if (cid < 34) { int r = cid-18; cb2 = r>>3; qx = r&7; q = gt;   nq = 4096; tp = fine; nt = 4096; om = chamC; }
      else               { int r = cid-34; cb2 = r>>3; qx = r&7; q = fine; nq = 4096; tp = gt;   nt = 4096; om = chamD; }
      const int qi = qx*512 + t;
      const float* qp = q + (size_t)(cb2*nq + qi)*3;
      float qxv = qp[0], qyv = qp[1], qzv = qp[2];
      float m = 3.4e38f;
      for (int tt0 = 0; tt0 < nt; tt0 += 1024) {
        int chunk = min(1024, nt - tt0);
        __syncthreads();
        for (int i = t; i < chunk; i += 512) {
          const float* pp = tp + (size_t)(cb2*nt + tt0 + i)*3;
          L.ch.x[i] = pp[0]; L.ch.y[i] = pp[1]; L.ch.z[i] = pp[2];
        }
        __syncthreads();
        for (int i = 0; i < chunk; ++i) {
          float dx = qxv-L.ch.x[i], dy = qyv-L.ch.y[i], dz = qzv-L.ch.z[i];
          float d = dx*dx + dy*dy + dz*dz;
          m = fminf(m, d);
        }
      }
      om[cb2*nq + qi] = m;
      signal_done(chamdone);
    } else {                                           // -------- output copies
      for (int i = (eb - 50)*512 + t; i < 27648; i += 14*512)
        out[i] = (i < 3072) ? coarse[i] : fine[i - 3072];
    }
    // -------- EMD1: 64 blocks x 32 rows --------
    const int b = eb >> 5, bxl = eb & 31;
    const int r0b = bxl * 32;
    const int iters = *itersPtr;
    const float* cb = coarse + (size_t)b*512*3;        // xtile == coarse with &511 wrap
    const float* pb = gtfps  + (size_t)b*1024*3;
    float* f1b = f1 + b*1024; float* g1b = g1 + b*1024; float* dv1b = dv1 + b*1024;
    waitcnt_ge(&fpsflag[b], 1u);                       // gtfps ready
    for (int ph = 0; ph < 8; ++ph) {
      const int k = ph >> 1;
      if (k < iters) {
        if (!(ph & 1))
          emd_pass_t<4>(cb, 511, pb, 1023, g1b, f1b, 1024, LOGN1, k > 0, r0b,
                        L.emd.tyx, L.emd.tyy, L.emd.tyz, L.emd.tg);
        else
          emd_pass_t<4>(pb, 1023, cb, 511, f1b, g1b, 1024, LOGN1, 1, r0b,
                        L.emd.tyx, L.emd.tyy, L.emd.tyz, L.emd.tg);
      }
      gbar(cnt1, gen1, 64u);
    }
    emd_final_t<4>(cb, 511, pb, 1023, g1b, dv1b, 1024, iters > 0, r0b,
                   L.emd.tyx, L.emd.tyy, L.emd.tyz, L.emd.tg);
    gbar(cnt1, gen1, 64u);                             // dv1 complete
    if (bxl == 0) {                                    // one finalizer per batch
      waitcnt_ge(done2, 128u);                         // dv2 complete
      waitcnt_ge(chamdone, 50u);                       // chamA-D complete
      finalize_body(b, chamA, chamB, chamC, chamD, dv1, dv2, out, L.emd.tyx);
    }
  }
}

extern "C" void kernel_launch(void* const* d_in, const int* in_sizes, int n_in,
                              void* d_out, int out_size, void* d_ws, size_t ws_size,
                              hipStream_t stream) {
  (void)in_sizes; (void)n_in; (void)out_size; (void)ws_size;
  const float* coarse = (const float*)d_in[0];
  const float* fine   = (const float*)d_in[1];
  const float* gt     = (const float*)d_in[2];
  const int*   iters  = (const int*)d_in[3];
  float* out = (float*)d_out;
  float* ws  = (float*)d_ws;

  float* chamA = ws + 0;        // 2*4096
  float* chamB = ws + 8192;     // 2*512
  float* chamC = ws + 9216;     // 2*4096
  float* chamD = ws + 17408;    // 2*4096
  float* f1    = ws + 25600;    // 2*1024
  float* g1    = ws + 27648;    // 2*1024
  float* dv1   = ws + 29696;    // 2*1024
  float* f2    = ws + 31744;    // 2*4096
  float* g2    = ws + 39936;    // 2*4096
  float* dv2   = ws + 48128;    // 2*4096
  float* gtfps = ws + 56320;    // 2*1024*3
  unsigned* sync = (unsigned*)(ws + 62464);  // 8 words

  init_sync<<<1, 64, 0, stream>>>(sync);
  everything<<<194, 512, 0, stream>>>(coarse, fine, gt, iters,
                                      chamA, chamB, chamC, chamD,
                                      f1, g1, dv1, f2, g2, dv2,
                                      gtfps, sync, out);
}